// Round 1
// baseline (244.495 us; speedup 1.0000x reference)
//
#include <hip/hip_runtime.h>
#include <hip/hip_cooperative_groups.h>

// Mutual information, N=8 images 384x384, 50 soft bins.
// R12 = R11 fused into ONE cooperative dispatch (was: memset + hgram + finalize).
//   - Phase 0: slice-0 blocks zero hg[8][32][32] + done-counter via AGENT-scope
//     atomic stores (per-XCD L2s are non-coherent; no kernel-boundary flush now).
//   - Main loop: identical to R11 (28 even sigmoid edges x256 -> f16 LDS,
//     16x16x32 MFMA, 3 blocks/CU single generation).
//   - grid.sync() orders zeroing before the 28x28 atomic epilogue.
//   - Per-block release-increment of done; block (0,0) acquire-spins to 768,
//     then runs finalize (W G W^T, marginals telescope, MI log-sum) with its
//     256 threads, LDS reused, hg read via agent-scope atomic loads.

#define D_TOTAL   147456
#define NBATCH    8
#define BINS      50
#define NEDGE     28                       // even edges j=-2..52
#define KSLICES   96                       // 768 blocks = 3/CU, single generation
#define KC        256                      // d-columns per block iteration
#define SLICE_LEN (D_TOTAL / KSLICES)      // 1536
#define ITERS     (SLICE_LEN / KC)         // 6
#define LDS_STR   280                      // 140 dwords = 12 mod 32: conflict-free b128 frags
#define NBLOCKS   (KSLICES * NBATCH)       // 768

typedef _Float16 half8  __attribute__((ext_vector_type(8)));
typedef __fp16   fp16x2 __attribute__((ext_vector_type(2)));   // cvt_pkrtz return type
typedef float    f32x4  __attribute__((ext_vector_type(4)));

struct Tab { float c[NEDGE]; };
constexpr Tab make_tab() {
    Tab t{};
    double c = 0.6703200460356393;          // e^{-0.4} (edge j=-2)
    const double lam = 1.4918246976412703;  // e^{0.4} between even edges
    for (int i = 0; i < NEDGE; ++i) { t.c[i] = (float)c; c *= lam; }
    return t;
}
constexpr Tab TAB = make_tab();

__global__ __launch_bounds__(256, 3) void mi_fused(const float* __restrict__ im1,
                                                   const float* __restrict__ im2,
                                                   float* __restrict__ hg,
                                                   float* __restrict__ out) {
    __shared__ __align__(16) _Float16 SH[2][32][LDS_STR];   // 35840 B; reused by finalize

    const int tid   = threadIdx.x;
    const int slice = blockIdx.x;
    const int n     = blockIdx.y;
    const int base  = n * D_TOTAL + slice * SLICE_LEN;
    unsigned* const done = (unsigned*)(hg + NBATCH * 1024);

    // ---- phase 0: zero hg + counter (agent-scope stores: straight to coherent point) ----
    if (slice == 0) {
        float* z = hg + n * 1024;
        for (int i = tid; i < 1024; i += 256)
            __hip_atomic_store(&z[i], 0.0f, __ATOMIC_RELAXED, __HIP_MEMORY_SCOPE_AGENT);
        if (n == 0 && tid == 0)
            __hip_atomic_store(done, 0u, __ATOMIC_RELAXED, __HIP_MEMORY_SCOPE_AGENT);
    }

    {   // zero pad rows 28..31 once (staging only rewrites rows 0..27)
        unsigned* px = (unsigned*)&SH[0][28][0];
        unsigned* py = (unsigned*)&SH[1][28][0];
        for (int i = tid; i < 4 * LDS_STR / 2; i += 256) { px[i] = 0u; py[i] = 0u; }
    }

    // staging: threads 0..127 stage X element-pair (2h, 2h+1); 128..255 stage Y
    const int h    = tid & 127;
    const int isY  = tid >> 7;
    const float2* src2 = (const float2*)((isY ? im2 : im1) + base);
    _Float16* plane = &SH[isY][0][0];
    _Float16* dst   = plane + 2 * h;            // pair base within row

    const int lane = tid & 63;
    const int w    = tid >> 6;
    const int r0   = (w & 1) << 4;              // G row strip (X edge)
    const int c0   = (w >> 1) << 4;             // G col strip (Y edge)
    const int frow = lane & 15;
    const int kg   = (lane >> 4) << 3;

    f32x4 acc = {0.f, 0.f, 0.f, 0.f};

    float2 v = src2[h];
    for (int it = 0; it < ITERS; ++it) {
        float2 nv = {0.f, 0.f};
        if (it + 1 < ITERS) nv = src2[(it + 1) * (KC / 2) + h];   // prefetch
        // ---- stage 2 elements: 28 even-edge sigmoids each (x256, f16, packed) ----
        {
            const float Ea = __builtin_amdgcn_exp2f(v.x * -14.426950408889634f); // e^{-10va}
            const float Eb = __builtin_amdgcn_exp2f(v.y * -14.426950408889634f); // e^{-10vb}
            #pragma unroll
            for (int i = 0; i < NEDGE; ++i) {
                const float c = TAB.c[i];       // compile-time literal
                float ta = __builtin_amdgcn_rcpf(__builtin_fmaf(c * Ea, 0.00390625f, 0.00390625f));
                float tb = __builtin_amdgcn_rcpf(__builtin_fmaf(c * Eb, 0.00390625f, 0.00390625f));
                fp16x2 p = __builtin_amdgcn_cvt_pkrtz(ta, tb);    // 256/(1+u) pair
                *(fp16x2*)(dst + i * LDS_STR) = p;                // one ds_write_b32
            }
        }
        __syncthreads();
        #pragma unroll
        for (int ks = 0; ks < 8; ++ks) {
            const int k0 = ks * 32 + kg;
            half8 a = *(const half8*)&SH[0][r0 + frow][k0];
            half8 b = *(const half8*)&SH[1][c0 + frow][k0];
            acc = __builtin_amdgcn_mfma_f32_16x16x32_f16(a, b, acc, 0, 0, 0);
        }
        __syncthreads();
        v = nv;
    }

    // ---- zeroing must be globally visible before any atomicAdd: one grid barrier.
    // All blocks arrive together (uniform work) -> cheap.
    __threadfence();
    cooperative_groups::this_grid().sync();

    // epilogue: atomic-add the 28x28 region of G (device-scope, coherent point)
    float* hgn = hg + n * 1024;
    const int gj = c0 + (lane & 15);
    const int ri = r0 + ((lane >> 4) << 2);
    if (gj < NEDGE) {
        #pragma unroll
        for (int r = 0; r < 4; ++r) {
            const int gi = ri + r;
            if (gi < NEDGE) atomicAdd(&hgn[gi * 32 + gj], acc[r]);
        }
    }

    __syncthreads();   // emits s_waitcnt vmcnt(0): all this block's atomics complete
    if (tid == 0)
        __hip_atomic_fetch_add(done, 1u, __ATOMIC_RELEASE, __HIP_MEMORY_SCOPE_AGENT);
    if (slice != 0 || n != 0) return;          // 767 blocks done; (0,0) finalizes

    if (tid == 0) {
        while (__hip_atomic_load(done, __ATOMIC_ACQUIRE, __HIP_MEMORY_SCOPE_AGENT) < (unsigned)NBLOCKS)
            __builtin_amdgcn_s_sleep(8);
    }
    __syncthreads();

    // ---- finalize with 256 threads; LDS carved from SH (8960 floats available) ----
    float* const F  = (float*)&SH[0][0][0];
    // Gs[b][r][c] = F[(b*28+r)*29+c]   : 6496 floats (stride 29 vs bank conflicts)
    // mx = F+6496 (400), my = F+6896 (400), red = F+7296 (4), sT = F[7300]
    float* const MX = F + 6496;
    float* const MY = F + 6896;
    #define GS(nn,rr,cc) F[((nn)*NEDGE+(rr))*29+(cc)]

    for (int idx = tid; idx < NBATCH * NEDGE * NEDGE; idx += 256) {
        int b   = idx / (NEDGE * NEDGE);
        int rem = idx - b * (NEDGE * NEDGE);
        int r = rem / NEDGE, c2 = rem - r * NEDGE;
        // agent-scope load: this CU's L1 holds stale zeros from phase 0
        GS(b, r, c2) = __hip_atomic_load(&hg[b * 1024 + r * 32 + c2],
                                         __ATOMIC_RELAXED, __HIP_MEMORY_SCOPE_AGENT);
    }
    __syncthreads();

    // marginals: 800 tasks, 4-MAC band-dot (W row applied to G*(e1-e26))
    for (int t = tid; t < 2 * NBATCH * BINS; t += 256) {
        const int which = (t >= NBATCH * BINS) ? 1 : 0;
        const int t2 = which ? t - NBATCH * BINS : t;
        const int b = t2 / BINS, bb = t2 - b * BINS;
        const int q = bb >> 1;
        float w0, w1, w2, w3;
        if (bb & 1) { w0 = -1.f; w1 = 9.f; w2 = -7.f; w3 = -1.f; }
        else        { w0 =  1.f; w1 = 7.f; w2 = -9.f; w3 =  1.f; }
        float m;
        if (which == 0) {
            m = w0 * (GS(b,q,1)   - GS(b,q,26))
              + w1 * (GS(b,q+1,1) - GS(b,q+1,26))
              + w2 * (GS(b,q+2,1) - GS(b,q+2,26))
              + w3 * (GS(b,q+3,1) - GS(b,q+3,26));
            MX[b * BINS + bb] = m * 0.0625f;
        } else {
            m = w0 * (GS(b,1,q)   - GS(b,26,q))
              + w1 * (GS(b,1,q+1) - GS(b,26,q+1))
              + w2 * (GS(b,1,q+2) - GS(b,26,q+2))
              + w3 * (GS(b,1,q+3) - GS(b,26,q+3));
            MY[b * BINS + bb] = m * 0.0625f;
        }
    }
    if (tid == 0) {
        float t = 0.f;
        for (int b = 0; b < NBATCH; ++b)
            t += GS(b,1,1) - GS(b,1,26) - GS(b,26,1) + GS(b,26,26);
        F[7300] = t;
    }
    __syncthreads();

    // MI pass: 2x2 entry blocks share one 4x4 G block (task = b, b-pair, c-pair)
    const float invT = 1.0f / F[7300];
    const float invT2 = invT * invT;
    float mi = 0.f;
    for (int task = tid; task < NBATCH * 25 * 25; task += 256) {
        const int b   = task / 625;
        const int rem = task - b * 625;
        const int bp = rem / 25, cp = rem - bp * 25;
        float g[4][4];
        #pragma unroll
        for (int r = 0; r < 4; ++r)
            #pragma unroll
            for (int s = 0; s < 4; ++s) g[r][s] = GS(b, bp + r, cp + s);
        float rde[4], rdo[4];
        #pragma unroll
        for (int r = 0; r < 4; ++r) {
            rde[r] =  g[r][0] + 7.f * g[r][1] - 9.f * g[r][2] + g[r][3];
            rdo[r] = -g[r][0] + 9.f * g[r][1] - 7.f * g[r][2] - g[r][3];
        }
        const float hee = ( rde[0] + 7.f*rde[1] - 9.f*rde[2] + rde[3]) * (1.f/256.f);
        const float heo = ( rdo[0] + 7.f*rdo[1] - 9.f*rdo[2] + rdo[3]) * (1.f/256.f);
        const float hoe = (-rde[0] + 9.f*rde[1] - 7.f*rde[2] - rde[3]) * (1.f/256.f);
        const float hoo = (-rdo[0] + 9.f*rdo[1] - 7.f*rdo[2] - rdo[3]) * (1.f/256.f);
        const int b0 = 2 * bp, c0f = 2 * cp;
        {
            float p = hee * invT, jo = MX[b * BINS + b0] * MY[b * BINS + c0f] * invT2;
            mi += p * (__logf(p + 1e-8f) - __logf(jo + 1e-8f));
        }
        {
            float p = heo * invT, jo = MX[b * BINS + b0] * MY[b * BINS + c0f + 1] * invT2;
            mi += p * (__logf(p + 1e-8f) - __logf(jo + 1e-8f));
        }
        {
            float p = hoe * invT, jo = MX[b * BINS + b0 + 1] * MY[b * BINS + c0f] * invT2;
            mi += p * (__logf(p + 1e-8f) - __logf(jo + 1e-8f));
        }
        {
            float p = hoo * invT, jo = MX[b * BINS + b0 + 1] * MY[b * BINS + c0f + 1] * invT2;
            mi += p * (__logf(p + 1e-8f) - __logf(jo + 1e-8f));
        }
    }
    #pragma unroll
    for (int o = 32; o > 0; o >>= 1) mi += __shfl_down(mi, o, 64);
    if ((tid & 63) == 0) F[7296 + (tid >> 6)] = mi;
    __syncthreads();
    if (tid == 0) out[0] = F[7296] + F[7297] + F[7298] + F[7299];
}

extern "C" void kernel_launch(void* const* d_in, const int* in_sizes, int n_in,
                              void* d_out, int out_size, void* d_ws, size_t ws_size,
                              hipStream_t stream) {
    const float* im1 = (const float*)d_in[0];
    const float* im2 = (const float*)d_in[1];
    float* out = (float*)d_out;
    float* hg  = (float*)d_ws;   // [8][32][32] f32 + done counter = 32 KB + 4 B

    void* args[4] = { (void*)&im1, (void*)&im2, (void*)&hg, (void*)&out };
    (void)hipLaunchCooperativeKernel((const void*)mi_fused,
                                     dim3(KSLICES, NBATCH), dim3(256),
                                     args, 0, stream);
}

// Round 2
// 94.996 us; speedup vs baseline: 2.5737x; 2.5737x over previous
//
#include <hip/hip_runtime.h>

// Mutual information, N=8 images 384x384, 50 soft bins.
// R13 = R11 structure (memset + hgram) with finalize fused via LAST-BLOCK
// pattern (R12's grid.sync/threadfence cost ~150us of idle-wave stall; reverted).
//   - memset dispatch zeroes hg[8][32][32] + done counter (32772 B).
//   - hgram: 28 even sigmoid edges per element (t_j = sigmoid(10v-0.2j), x256),
//     G = te_x . te_y^T via 16x16x32 MFMA, atomic 28x28 epilogue (device scope,
//     performed at the coherent point).
//   - __syncthreads() drains vmcnt (atomics complete), then tid0 does a RELAXED
//     agent-scope fetch_add(done). old==767 -> this block runs finalize with its
//     256 threads, reading hg via agent-scope loads (its caches never held hg).
//     767 blocks exit: no spin, no grid barrier, no fences.
//   - finalize: hgram = W G W^T, W = D*M (cubic-interp odd edges, 4-banded
//     {1,7,-9,1}/16 even, {-1,9,-7,-1}/16 odd); marginals telescope; MI log-sum.

#define D_TOTAL   147456
#define NBATCH    8
#define BINS      50
#define NEDGE     28                       // even edges j=-2..52
#define KSLICES   96                       // 768 blocks = 3/CU, single generation
#define KC        256                      // d-columns per block iteration
#define SLICE_LEN (D_TOTAL / KSLICES)      // 1536
#define ITERS     (SLICE_LEN / KC)         // 6
#define LDS_STR   280                      // 140 dwords = 12 mod 32: conflict-free b128 frags
#define NBLOCKS   (KSLICES * NBATCH)       // 768

typedef _Float16 half8  __attribute__((ext_vector_type(8)));
typedef __fp16   fp16x2 __attribute__((ext_vector_type(2)));   // cvt_pkrtz return type
typedef float    f32x4  __attribute__((ext_vector_type(4)));

struct Tab { float c[NEDGE]; };
constexpr Tab make_tab() {
    Tab t{};
    double c = 0.6703200460356393;          // e^{-0.4} (edge j=-2)
    const double lam = 1.4918246976412703;  // e^{0.4} between even edges
    for (int i = 0; i < NEDGE; ++i) { t.c[i] = (float)c; c *= lam; }
    return t;
}
constexpr Tab TAB = make_tab();

__global__ __launch_bounds__(256, 3) void mi_fused(const float* __restrict__ im1,
                                                   const float* __restrict__ im2,
                                                   float* __restrict__ hg,
                                                   float* __restrict__ out) {
    __shared__ __align__(16) _Float16 SH[2][32][LDS_STR];   // 35840 B; reused by finalize
    __shared__ unsigned s_last;

    const int tid   = threadIdx.x;
    const int slice = blockIdx.x;
    const int n     = blockIdx.y;
    const int base  = n * D_TOTAL + slice * SLICE_LEN;
    unsigned* const done = (unsigned*)(hg + NBATCH * 1024);

    {   // zero pad rows 28..31 once (staging only rewrites rows 0..27)
        unsigned* px = (unsigned*)&SH[0][28][0];
        unsigned* py = (unsigned*)&SH[1][28][0];
        for (int i = tid; i < 4 * LDS_STR / 2; i += 256) { px[i] = 0u; py[i] = 0u; }
    }

    // staging: threads 0..127 stage X element-pair (2h, 2h+1); 128..255 stage Y
    const int h    = tid & 127;
    const int isY  = tid >> 7;
    const float2* src2 = (const float2*)((isY ? im2 : im1) + base);
    _Float16* plane = &SH[isY][0][0];
    _Float16* dst   = plane + 2 * h;            // pair base within row

    const int lane = tid & 63;
    const int w    = tid >> 6;
    const int r0   = (w & 1) << 4;              // G row strip (X edge)
    const int c0   = (w >> 1) << 4;             // G col strip (Y edge)
    const int frow = lane & 15;
    const int kg   = (lane >> 4) << 3;

    f32x4 acc = {0.f, 0.f, 0.f, 0.f};

    float2 v = src2[h];
    for (int it = 0; it < ITERS; ++it) {
        float2 nv = {0.f, 0.f};
        if (it + 1 < ITERS) nv = src2[(it + 1) * (KC / 2) + h];   // prefetch
        // ---- stage 2 elements: 28 even-edge sigmoids each (x256, f16, packed) ----
        {
            const float Ea = __builtin_amdgcn_exp2f(v.x * -14.426950408889634f); // e^{-10va}
            const float Eb = __builtin_amdgcn_exp2f(v.y * -14.426950408889634f); // e^{-10vb}
            #pragma unroll
            for (int i = 0; i < NEDGE; ++i) {
                const float c = TAB.c[i];       // compile-time literal
                float ta = __builtin_amdgcn_rcpf(__builtin_fmaf(c * Ea, 0.00390625f, 0.00390625f));
                float tb = __builtin_amdgcn_rcpf(__builtin_fmaf(c * Eb, 0.00390625f, 0.00390625f));
                fp16x2 p = __builtin_amdgcn_cvt_pkrtz(ta, tb);    // 256/(1+u) pair
                *(fp16x2*)(dst + i * LDS_STR) = p;                // one ds_write_b32
            }
        }
        __syncthreads();
        #pragma unroll
        for (int ks = 0; ks < 8; ++ks) {
            const int k0 = ks * 32 + kg;
            half8 a = *(const half8*)&SH[0][r0 + frow][k0];
            half8 b = *(const half8*)&SH[1][c0 + frow][k0];
            acc = __builtin_amdgcn_mfma_f32_16x16x32_f16(a, b, acc, 0, 0, 0);
        }
        __syncthreads();
        v = nv;
    }

    // epilogue: atomic-add the 28x28 region of G (device scope -> coherent point)
    float* hgn = hg + n * 1024;
    const int gj = c0 + (lane & 15);
    const int ri = r0 + ((lane >> 4) << 2);
    if (gj < NEDGE) {
        #pragma unroll
        for (int r = 0; r < 4; ++r) {
            const int gi = ri + r;
            if (gi < NEDGE) atomicAdd(&hgn[gi * 32 + gj], acc[r]);
        }
    }

    // __syncthreads: compiler emits s_waitcnt vmcnt(0) before s_barrier ->
    // every wave's atomics in this block are COMPLETE (performed at the
    // coherent point) before tid0's increment below. Also frees SH for reuse.
    __syncthreads();
    if (tid == 0) {
        unsigned old = __hip_atomic_fetch_add(done, 1u, __ATOMIC_RELAXED,
                                              __HIP_MEMORY_SCOPE_AGENT);
        s_last = (old == (unsigned)(NBLOCKS - 1)) ? 1u : 0u;
    }
    __syncthreads();
    if (!s_last) return;                       // 767 blocks exit; last finalizes

    // ---- finalize with 256 threads; LDS carved from SH (8960 floats available) ----
    float* const F  = (float*)&SH[0][0][0];
    // Gs[b][r][c] = F[(b*28+r)*29+c]   : 6496 floats (stride 29 vs bank conflicts)
    // mx = F+6496 (400), my = F+6896 (400), red = F+7296 (4), sT = F[7300]
    float* const MX = F + 6496;
    float* const MY = F + 6896;
    #define GS(nn,rr,cc) F[((nn)*NEDGE+(rr))*29+(cc)]

    for (int idx = tid; idx < NBATCH * NEDGE * NEDGE; idx += 256) {
        int b   = idx / (NEDGE * NEDGE);
        int rem = idx - b * (NEDGE * NEDGE);
        int r = rem / NEDGE, c2 = rem - r * NEDGE;
        // agent-scope load: read the coherent point (L1/L2 never cached hg here)
        GS(b, r, c2) = __hip_atomic_load(&hg[b * 1024 + r * 32 + c2],
                                         __ATOMIC_RELAXED, __HIP_MEMORY_SCOPE_AGENT);
    }
    __syncthreads();

    // marginals: 800 tasks, 4-MAC band-dot (W row applied to G*(e1-e26))
    for (int t = tid; t < 2 * NBATCH * BINS; t += 256) {
        const int which = (t >= NBATCH * BINS) ? 1 : 0;
        const int t2 = which ? t - NBATCH * BINS : t;
        const int b = t2 / BINS, bb = t2 - b * BINS;
        const int q = bb >> 1;
        float w0, w1, w2, w3;
        if (bb & 1) { w0 = -1.f; w1 = 9.f; w2 = -7.f; w3 = -1.f; }
        else        { w0 =  1.f; w1 = 7.f; w2 = -9.f; w3 =  1.f; }
        float m;
        if (which == 0) {
            m = w0 * (GS(b,q,1)   - GS(b,q,26))
              + w1 * (GS(b,q+1,1) - GS(b,q+1,26))
              + w2 * (GS(b,q+2,1) - GS(b,q+2,26))
              + w3 * (GS(b,q+3,1) - GS(b,q+3,26));
            MX[b * BINS + bb] = m * 0.0625f;
        } else {
            m = w0 * (GS(b,1,q)   - GS(b,26,q))
              + w1 * (GS(b,1,q+1) - GS(b,26,q+1))
              + w2 * (GS(b,1,q+2) - GS(b,26,q+2))
              + w3 * (GS(b,1,q+3) - GS(b,26,q+3));
            MY[b * BINS + bb] = m * 0.0625f;
        }
    }
    if (tid == 0) {
        float t = 0.f;
        for (int b = 0; b < NBATCH; ++b)
            t += GS(b,1,1) - GS(b,1,26) - GS(b,26,1) + GS(b,26,26);
        F[7300] = t;
    }
    __syncthreads();

    // MI pass: 2x2 entry blocks share one 4x4 G block (task = b, b-pair, c-pair)
    const float invT = 1.0f / F[7300];
    const float invT2 = invT * invT;
    float mi = 0.f;
    for (int task = tid; task < NBATCH * 25 * 25; task += 256) {
        const int b   = task / 625;
        const int rem = task - b * 625;
        const int bp = rem / 25, cp = rem - bp * 25;
        float g[4][4];
        #pragma unroll
        for (int r = 0; r < 4; ++r)
            #pragma unroll
            for (int s = 0; s < 4; ++s) g[r][s] = GS(b, bp + r, cp + s);
        float rde[4], rdo[4];
        #pragma unroll
        for (int r = 0; r < 4; ++r) {
            rde[r] =  g[r][0] + 7.f * g[r][1] - 9.f * g[r][2] + g[r][3];
            rdo[r] = -g[r][0] + 9.f * g[r][1] - 7.f * g[r][2] - g[r][3];
        }
        const float hee = ( rde[0] + 7.f*rde[1] - 9.f*rde[2] + rde[3]) * (1.f/256.f);
        const float heo = ( rdo[0] + 7.f*rdo[1] - 9.f*rdo[2] + rdo[3]) * (1.f/256.f);
        const float hoe = (-rde[0] + 9.f*rde[1] - 7.f*rde[2] - rde[3]) * (1.f/256.f);
        const float hoo = (-rdo[0] + 9.f*rdo[1] - 7.f*rdo[2] - rdo[3]) * (1.f/256.f);
        const int b0 = 2 * bp, c0f = 2 * cp;
        {
            float p = hee * invT, jo = MX[b * BINS + b0] * MY[b * BINS + c0f] * invT2;
            mi += p * (__logf(p + 1e-8f) - __logf(jo + 1e-8f));
        }
        {
            float p = heo * invT, jo = MX[b * BINS + b0] * MY[b * BINS + c0f + 1] * invT2;
            mi += p * (__logf(p + 1e-8f) - __logf(jo + 1e-8f));
        }
        {
            float p = hoe * invT, jo = MX[b * BINS + b0 + 1] * MY[b * BINS + c0f] * invT2;
            mi += p * (__logf(p + 1e-8f) - __logf(jo + 1e-8f));
        }
        {
            float p = hoo * invT, jo = MX[b * BINS + b0 + 1] * MY[b * BINS + c0f + 1] * invT2;
            mi += p * (__logf(p + 1e-8f) - __logf(jo + 1e-8f));
        }
    }
    #pragma unroll
    for (int o = 32; o > 0; o >>= 1) mi += __shfl_down(mi, o, 64);
    if ((tid & 63) == 0) F[7296 + (tid >> 6)] = mi;
    __syncthreads();
    if (tid == 0) out[0] = F[7296] + F[7297] + F[7298] + F[7299];
}

extern "C" void kernel_launch(void* const* d_in, const int* in_sizes, int n_in,
                              void* d_out, int out_size, void* d_ws, size_t ws_size,
                              hipStream_t stream) {
    const float* im1 = (const float*)d_in[0];
    const float* im2 = (const float*)d_in[1];
    float* out = (float*)d_out;
    float* hg  = (float*)d_ws;   // [8][32][32] f32 + done counter = 32 KB + 4 B

    (void)hipMemsetAsync(d_ws, 0, NBATCH * 1024 * sizeof(float) + sizeof(unsigned), stream);
    mi_fused<<<dim3(KSLICES, NBATCH), dim3(256), 0, stream>>>(im1, im2, hg, out);
}

// Round 3
// 82.101 us; speedup vs baseline: 2.9780x; 1.1571x over previous
//
#include <hip/hip_runtime.h>

// Mutual information, N=8 images 384x384, 50 soft bins.
// R14 = R0/R11 3-dispatch structure (fusions R12/R13 both regressed) with the
// hgram MFMA restructured from 4x quadrant 16x16x32 to 4x k-split 32x32x16:
// each wave owns a 64-wide k-quarter and accumulates the FULL 32x32 G partial
// in 16 regs -> ds_read_b128 per block-iter drops 64 -> 32 (each X/Y slab read
// once, not twice). Partials reduced via LDS (Xs reused) then same 28x28
// atomic epilogue. Loop is LDS-inst-bound: 1328 -> ~944 LDS cyc/block-iter.
//
// K1 hgram: 28 even sigmoid edges per element (t_j = sigmoid(10v-0.2j), x256),
//   G = te_x . te_y^T via 32x32x16 MFMA, atomic 28x28 epilogue
//   into hg[8][32][32] (zeroed by a 32KB memset dispatch).
// K2 finalize (1 block, 1024 thr): hgram = W G W^T, W = D*M (cubic-interp odd
//   edges, 4-banded {1,7,-9,1}/16 even, {-1,9,-7,-1}/16 odd); marginals
//   telescope (sum_b W[b] = e_1 - e_26); MI log-sum.

#define D_TOTAL   147456
#define NBATCH    8
#define BINS      50
#define NEDGE     28                       // even edges j=-2..52
#define KSLICES   96                       // 768 blocks = 3/CU, single generation
#define KC        256                      // d-columns per block iteration
#define SLICE_LEN (D_TOTAL / KSLICES)      // 1536
#define ITERS     (SLICE_LEN / KC)         // 6
#define LDS_STR   280                      // 140 dwords = 12 mod 32: conflict-free b128 frags

typedef _Float16 half8  __attribute__((ext_vector_type(8)));
typedef __fp16   fp16x2 __attribute__((ext_vector_type(2)));   // cvt_pkrtz return type
typedef float    f32x16 __attribute__((ext_vector_type(16)));

struct Tab { float c[NEDGE]; };
constexpr Tab make_tab() {
    Tab t{};
    double c = 0.6703200460356393;          // e^{-0.4} (edge j=-2)
    const double lam = 1.4918246976412703;  // e^{0.4} between even edges
    for (int i = 0; i < NEDGE; ++i) { t.c[i] = (float)c; c *= lam; }
    return t;
}
constexpr Tab TAB = make_tab();

__global__ __launch_bounds__(256, 3) void hgram_kernel(const float* __restrict__ im1,
                                                       const float* __restrict__ im2,
                                                       float* __restrict__ hg) {
    __shared__ __align__(16) _Float16 Xs[32][LDS_STR];
    __shared__ __align__(16) _Float16 Ys[32][LDS_STR];

    const int tid   = threadIdx.x;
    const int slice = blockIdx.x;
    const int n     = blockIdx.y;
    const int base  = n * D_TOTAL + slice * SLICE_LEN;

    {   // zero pad rows 28..31 once (staging only rewrites rows 0..27)
        unsigned* px = (unsigned*)&Xs[28][0];
        unsigned* py = (unsigned*)&Ys[28][0];
        for (int i = tid; i < 4 * LDS_STR / 2; i += 256) { px[i] = 0u; py[i] = 0u; }
    }

    // staging: threads 0..127 stage X element-pair (2h, 2h+1); 128..255 stage Y
    const int h    = tid & 127;
    const int isY  = tid >> 7;
    const float2* src2 = (const float2*)((isY ? im2 : im1) + base);
    _Float16* plane = isY ? &Ys[0][0] : &Xs[0][0];
    _Float16* dst   = plane + 2 * h;            // pair base within row

    const int lane  = tid & 63;
    const int w     = tid >> 6;
    const int kw    = w << 6;                   // wave's 64-wide k-quarter
    const int row32 = lane & 31;                // A row / B col (edge index)
    const int kg    = (lane >> 5) << 3;         // k sub-offset: 0 or 8

    f32x16 acc = {0.f,0.f,0.f,0.f,0.f,0.f,0.f,0.f,
                  0.f,0.f,0.f,0.f,0.f,0.f,0.f,0.f};

    float2 v = src2[h];
    for (int it = 0; it < ITERS; ++it) {
        float2 nv = {0.f, 0.f};
        if (it + 1 < ITERS) nv = src2[(it + 1) * (KC / 2) + h];   // prefetch
        // ---- stage 2 elements: 28 even-edge sigmoids each (x256, f16, packed) ----
        {
            const float Ea = __builtin_amdgcn_exp2f(v.x * -14.426950408889634f); // e^{-10va}
            const float Eb = __builtin_amdgcn_exp2f(v.y * -14.426950408889634f); // e^{-10vb}
            #pragma unroll
            for (int i = 0; i < NEDGE; ++i) {
                const float c = TAB.c[i];       // compile-time literal
                float ta = __builtin_amdgcn_rcpf(__builtin_fmaf(c * Ea, 0.00390625f, 0.00390625f));
                float tb = __builtin_amdgcn_rcpf(__builtin_fmaf(c * Eb, 0.00390625f, 0.00390625f));
                fp16x2 p = __builtin_amdgcn_cvt_pkrtz(ta, tb);    // 256/(1+u) pair
                *(fp16x2*)(dst + i * LDS_STR) = p;                // one ds_write_b32
            }
        }
        __syncthreads();
        // ---- 32x32x16 MFMA over this wave's k-quarter: 8 ds_read_b128 total ----
        #pragma unroll
        for (int s = 0; s < 4; ++s) {
            const int k0 = kw + s * 16 + kg;
            half8 a = *(const half8*)&Xs[row32][k0];
            half8 b = *(const half8*)&Ys[row32][k0];
            acc = __builtin_amdgcn_mfma_f32_32x32x16_f16(a, b, acc, 0, 0, 0);
        }
        __syncthreads();
        v = nv;
    }

    // ---- reduce 4 per-wave partials via LDS (Xs reused; last barrier passed) ----
    float* const Pf = (float*)&Xs[0][0];        // 4*32*32 f32 = 16 KB <= 17.9 KB
    {
        float* Pw = Pf + (w << 10);
        const int prow_base = (lane >> 5) << 2; // 0 or 4
        #pragma unroll
        for (int reg = 0; reg < 16; ++reg) {
            const int prow = (reg & 3) + ((reg >> 2) << 3) + prow_base;
            Pw[prow * 32 + row32] = acc[reg];   // C/D: col=lane&31, verified map
        }
    }
    __syncthreads();

    // epilogue: sum partials, atomic-add the 28x28 region of G
    float* hgn = hg + n * 1024;
    for (int e = tid; e < 1024; e += 256) {
        const int r = e >> 5, c = e & 31;
        if (r < NEDGE && c < NEDGE) {
            float s = Pf[e] + Pf[1024 + e] + Pf[2048 + e] + Pf[3072 + e];
            atomicAdd(&hgn[e], s);
        }
    }
}

__global__ __launch_bounds__(1024) void finalize_kernel(const float* __restrict__ hg,
                                                        float* __restrict__ out) {
    __shared__ float Gs[NBATCH][NEDGE][29];   // stride 29 vs bank conflicts
    __shared__ float mx[NBATCH][BINS], my[NBATCH][BINS];
    __shared__ float red[16];
    __shared__ float sT;
    const int tid = threadIdx.x;

    for (int idx = tid; idx < NBATCH * NEDGE * NEDGE; idx += 1024) {
        int n = idx / (NEDGE * NEDGE);
        int rem = idx - n * (NEDGE * NEDGE);
        int r = rem / NEDGE, c = rem - r * NEDGE;
        Gs[n][r][c] = hg[n * 1024 + r * 32 + c];
    }
    __syncthreads();

    // marginals: 800 tasks, 4-MAC band-dot (W row applied to G*(e1-e26))
    if (tid < 2 * NBATCH * BINS) {
        const int which = (tid >= NBATCH * BINS) ? 1 : 0;
        const int t2 = which ? tid - NBATCH * BINS : tid;
        const int n = t2 / BINS, b = t2 - n * BINS;
        const int q = b >> 1;
        float w0, w1, w2, w3;
        if (b & 1) { w0 = -1.f; w1 = 9.f; w2 = -7.f; w3 = -1.f; }
        else       { w0 =  1.f; w1 = 7.f; w2 = -9.f; w3 =  1.f; }
        float m;
        if (which == 0) {
            m = w0 * (Gs[n][q][1]   - Gs[n][q][26])
              + w1 * (Gs[n][q+1][1] - Gs[n][q+1][26])
              + w2 * (Gs[n][q+2][1] - Gs[n][q+2][26])
              + w3 * (Gs[n][q+3][1] - Gs[n][q+3][26]);
            mx[n][b] = m * 0.0625f;
        } else {
            m = w0 * (Gs[n][1][q]   - Gs[n][26][q])
              + w1 * (Gs[n][1][q+1] - Gs[n][26][q+1])
              + w2 * (Gs[n][1][q+2] - Gs[n][26][q+2])
              + w3 * (Gs[n][1][q+3] - Gs[n][26][q+3]);
            my[n][b] = m * 0.0625f;
        }
    }
    if (tid == 0) {
        float t = 0.f;
        for (int n = 0; n < NBATCH; ++n)
            t += Gs[n][1][1] - Gs[n][1][26] - Gs[n][26][1] + Gs[n][26][26];
        sT = t;
    }
    __syncthreads();

    // MI pass: 2x2 entry blocks share one 4x4 G block (task = n, b-pair, c-pair)
    const float invT = 1.0f / sT;
    const float invT2 = invT * invT;
    float mi = 0.f;
    for (int task = tid; task < NBATCH * 25 * 25; task += 1024) {
        const int n = task / 625;
        const int rem = task - n * 625;
        const int bp = rem / 25, cp = rem - bp * 25;
        float g[4][4];
        #pragma unroll
        for (int r = 0; r < 4; ++r)
            #pragma unroll
            for (int s = 0; s < 4; ++s) g[r][s] = Gs[n][bp + r][cp + s];
        float rde[4], rdo[4];
        #pragma unroll
        for (int r = 0; r < 4; ++r) {
            rde[r] =  g[r][0] + 7.f * g[r][1] - 9.f * g[r][2] + g[r][3];
            rdo[r] = -g[r][0] + 9.f * g[r][1] - 7.f * g[r][2] - g[r][3];
        }
        const float hee = ( rde[0] + 7.f*rde[1] - 9.f*rde[2] + rde[3]) * (1.f/256.f);
        const float heo = ( rdo[0] + 7.f*rdo[1] - 9.f*rdo[2] + rdo[3]) * (1.f/256.f);
        const float hoe = (-rde[0] + 9.f*rde[1] - 7.f*rde[2] - rde[3]) * (1.f/256.f);
        const float hoo = (-rdo[0] + 9.f*rdo[1] - 7.f*rdo[2] - rdo[3]) * (1.f/256.f);
        const int b0 = 2 * bp, c0 = 2 * cp;
        {
            float p = hee * invT, jo = mx[n][b0] * my[n][c0] * invT2;
            mi += p * (__logf(p + 1e-8f) - __logf(jo + 1e-8f));
        }
        {
            float p = heo * invT, jo = mx[n][b0] * my[n][c0 + 1] * invT2;
            mi += p * (__logf(p + 1e-8f) - __logf(jo + 1e-8f));
        }
        {
            float p = hoe * invT, jo = mx[n][b0 + 1] * my[n][c0] * invT2;
            mi += p * (__logf(p + 1e-8f) - __logf(jo + 1e-8f));
        }
        {
            float p = hoo * invT, jo = mx[n][b0 + 1] * my[n][c0 + 1] * invT2;
            mi += p * (__logf(p + 1e-8f) - __logf(jo + 1e-8f));
        }
    }
    #pragma unroll
    for (int o = 32; o > 0; o >>= 1) mi += __shfl_down(mi, o, 64);
    if ((tid & 63) == 0) red[tid >> 6] = mi;
    __syncthreads();
    if (tid == 0) {
        float t = 0.f;
        for (int i = 0; i < 16; ++i) t += red[i];
        out[0] = t;
    }
}

extern "C" void kernel_launch(void* const* d_in, const int* in_sizes, int n_in,
                              void* d_out, int out_size, void* d_ws, size_t ws_size,
                              hipStream_t stream) {
    const float* im1 = (const float*)d_in[0];
    const float* im2 = (const float*)d_in[1];
    float* out = (float*)d_out;
    float* hg  = (float*)d_ws;   // [8][32][32] f32 = 32 KB

    (void)hipMemsetAsync(d_ws, 0, NBATCH * 1024 * sizeof(float), stream);
    hgram_kernel<<<dim3(KSLICES, NBATCH), dim3(256), 0, stream>>>(im1, im2, hg);
    finalize_kernel<<<dim3(1), dim3(1024), 0, stream>>>(hg, out);
}

// Round 4
// 75.184 us; speedup vs baseline: 3.2520x; 1.0920x over previous
//
#include <hip/hip_runtime.h>

// Mutual information, N=8 images 384x384, 50 soft bins.
// R15 = R14 with finalize parallelized: 8 blocks (one per image) x 1024 thr.
// T (batch-global normalizer) telescopes to 4 G-corner reads per image, so each
// block computes it independently from global; mi_n accumulated into out[0] via
// atomicAdd. out[0] zeroed by a plain store in hgram block (0,0) (kernel
// boundary orders it). hgram identical to R14 (k-split 32x32x16 MFMA, LDS
// partial reduce, 28x28 atomic epilogue into memset-zeroed hg[8][32][32]).
//
// K1 hgram: 28 even sigmoid edges per element (t_j = sigmoid(10v-0.2j), x256),
//   G = te_x . te_y^T via 32x32x16 MFMA (each wave owns a 64-wide k-quarter,
//   full 32x32 partial in 16 regs; X/Y slabs each written once + read once).
// K2 finalize (8 blocks): hgram = W G W^T, W = D*M (cubic-interp odd edges,
//   4-banded {1,7,-9,1}/16 even, {-1,9,-7,-1}/16 odd); marginals telescope
//   (sum_b W[b] = e_1 - e_26); MI log-sum; atomicAdd to out.

#define D_TOTAL   147456
#define NBATCH    8
#define BINS      50
#define NEDGE     28                       // even edges j=-2..52
#define KSLICES   96                       // 768 blocks = 3/CU, single generation
#define KC        256                      // d-columns per block iteration
#define SLICE_LEN (D_TOTAL / KSLICES)      // 1536
#define ITERS     (SLICE_LEN / KC)         // 6
#define LDS_STR   280                      // 140 dwords = 12 mod 32: conflict-free b128 frags

typedef _Float16 half8  __attribute__((ext_vector_type(8)));
typedef __fp16   fp16x2 __attribute__((ext_vector_type(2)));   // cvt_pkrtz return type
typedef float    f32x16 __attribute__((ext_vector_type(16)));

struct Tab { float c[NEDGE]; };
constexpr Tab make_tab() {
    Tab t{};
    double c = 0.6703200460356393;          // e^{-0.4} (edge j=-2)
    const double lam = 1.4918246976412703;  // e^{0.4} between even edges
    for (int i = 0; i < NEDGE; ++i) { t.c[i] = (float)c; c *= lam; }
    return t;
}
constexpr Tab TAB = make_tab();

__global__ __launch_bounds__(256, 3) void hgram_kernel(const float* __restrict__ im1,
                                                       const float* __restrict__ im2,
                                                       float* __restrict__ hg,
                                                       float* __restrict__ out) {
    __shared__ __align__(16) _Float16 Xs[32][LDS_STR];
    __shared__ __align__(16) _Float16 Ys[32][LDS_STR];

    const int tid   = threadIdx.x;
    const int slice = blockIdx.x;
    const int n     = blockIdx.y;
    const int base  = n * D_TOTAL + slice * SLICE_LEN;

    if (slice == 0 && n == 0 && tid == 0) out[0] = 0.f;   // ordered by kernel boundary

    {   // zero pad rows 28..31 once (staging only rewrites rows 0..27)
        unsigned* px = (unsigned*)&Xs[28][0];
        unsigned* py = (unsigned*)&Ys[28][0];
        for (int i = tid; i < 4 * LDS_STR / 2; i += 256) { px[i] = 0u; py[i] = 0u; }
    }

    // staging: threads 0..127 stage X element-pair (2h, 2h+1); 128..255 stage Y
    const int h    = tid & 127;
    const int isY  = tid >> 7;
    const float2* src2 = (const float2*)((isY ? im2 : im1) + base);
    _Float16* plane = isY ? &Ys[0][0] : &Xs[0][0];
    _Float16* dst   = plane + 2 * h;            // pair base within row

    const int lane  = tid & 63;
    const int w     = tid >> 6;
    const int kw    = w << 6;                   // wave's 64-wide k-quarter
    const int row32 = lane & 31;                // A row / B col (edge index)
    const int kg    = (lane >> 5) << 3;         // k sub-offset: 0 or 8

    f32x16 acc = {0.f,0.f,0.f,0.f,0.f,0.f,0.f,0.f,
                  0.f,0.f,0.f,0.f,0.f,0.f,0.f,0.f};

    float2 v = src2[h];
    for (int it = 0; it < ITERS; ++it) {
        float2 nv = {0.f, 0.f};
        if (it + 1 < ITERS) nv = src2[(it + 1) * (KC / 2) + h];   // prefetch
        // ---- stage 2 elements: 28 even-edge sigmoids each (x256, f16, packed) ----
        {
            const float Ea = __builtin_amdgcn_exp2f(v.x * -14.426950408889634f); // e^{-10va}
            const float Eb = __builtin_amdgcn_exp2f(v.y * -14.426950408889634f); // e^{-10vb}
            #pragma unroll
            for (int i = 0; i < NEDGE; ++i) {
                const float c = TAB.c[i];       // compile-time literal
                float ta = __builtin_amdgcn_rcpf(__builtin_fmaf(c * Ea, 0.00390625f, 0.00390625f));
                float tb = __builtin_amdgcn_rcpf(__builtin_fmaf(c * Eb, 0.00390625f, 0.00390625f));
                fp16x2 p = __builtin_amdgcn_cvt_pkrtz(ta, tb);    // 256/(1+u) pair
                *(fp16x2*)(dst + i * LDS_STR) = p;                // one ds_write_b32
            }
        }
        __syncthreads();
        // ---- 32x32x16 MFMA over this wave's k-quarter: 8 ds_read_b128 total ----
        #pragma unroll
        for (int s = 0; s < 4; ++s) {
            const int k0 = kw + s * 16 + kg;
            half8 a = *(const half8*)&Xs[row32][k0];
            half8 b = *(const half8*)&Ys[row32][k0];
            acc = __builtin_amdgcn_mfma_f32_32x32x16_f16(a, b, acc, 0, 0, 0);
        }
        __syncthreads();
        v = nv;
    }

    // ---- reduce 4 per-wave partials via LDS (Xs reused; last barrier passed) ----
    float* const Pf = (float*)&Xs[0][0];        // 4*32*32 f32 = 16 KB <= 17.9 KB
    {
        float* Pw = Pf + (w << 10);
        const int prow_base = (lane >> 5) << 2; // 0 or 4
        #pragma unroll
        for (int reg = 0; reg < 16; ++reg) {
            const int prow = (reg & 3) + ((reg >> 2) << 3) + prow_base;
            Pw[prow * 32 + row32] = acc[reg];   // C/D: col=lane&31, verified map
        }
    }
    __syncthreads();

    // epilogue: sum partials, atomic-add the 28x28 region of G
    float* hgn = hg + n * 1024;
    for (int e = tid; e < 1024; e += 256) {
        const int r = e >> 5, c = e & 31;
        if (r < NEDGE && c < NEDGE) {
            float s = Pf[e] + Pf[1024 + e] + Pf[2048 + e] + Pf[3072 + e];
            atomicAdd(&hgn[e], s);
        }
    }
}

__global__ __launch_bounds__(1024) void finalize_kernel(const float* __restrict__ hg,
                                                        float* __restrict__ out) {
    __shared__ float Gs[NEDGE][29];           // own-n G, stride 29 vs bank conflicts
    __shared__ float mx[BINS], my[BINS];
    __shared__ float red[16];
    __shared__ float sT;
    const int tid = threadIdx.x;
    const int n   = blockIdx.x;
    const float* hgn = hg + n * 1024;

    for (int idx = tid; idx < NEDGE * NEDGE; idx += 1024) {
        int r = idx / NEDGE, c = idx - r * NEDGE;
        Gs[r][c] = hgn[r * 32 + c];
    }
    if (tid == 0) {   // batch-global T: telescoped corners of all 8 images
        float t = 0.f;
        #pragma unroll
        for (int b = 0; b < NBATCH; ++b) {
            const float* p = hg + b * 1024;
            t += p[1 * 32 + 1] - p[1 * 32 + 26] - p[26 * 32 + 1] + p[26 * 32 + 26];
        }
        sT = t;
    }
    __syncthreads();

    // marginals: 100 tasks, 4-MAC band-dot (W row applied to G*(e1-e26))
    if (tid < 2 * BINS) {
        const int which = (tid >= BINS) ? 1 : 0;
        const int b = which ? tid - BINS : tid;
        const int q = b >> 1;
        float w0, w1, w2, w3;
        if (b & 1) { w0 = -1.f; w1 = 9.f; w2 = -7.f; w3 = -1.f; }
        else       { w0 =  1.f; w1 = 7.f; w2 = -9.f; w3 =  1.f; }
        float m;
        if (which == 0) {
            m = w0 * (Gs[q][1]   - Gs[q][26])
              + w1 * (Gs[q+1][1] - Gs[q+1][26])
              + w2 * (Gs[q+2][1] - Gs[q+2][26])
              + w3 * (Gs[q+3][1] - Gs[q+3][26]);
            mx[b] = m * 0.0625f;
        } else {
            m = w0 * (Gs[1][q]   - Gs[26][q])
              + w1 * (Gs[1][q+1] - Gs[26][q+1])
              + w2 * (Gs[1][q+2] - Gs[26][q+2])
              + w3 * (Gs[1][q+3] - Gs[26][q+3]);
            my[b] = m * 0.0625f;
        }
    }
    __syncthreads();

    // MI pass: 2x2 entry blocks share one 4x4 G block (task = b-pair, c-pair)
    const float invT = 1.0f / sT;
    const float invT2 = invT * invT;
    float mi = 0.f;
    for (int task = tid; task < 25 * 25; task += 1024) {
        const int bp = task / 25, cp = task - bp * 25;
        float g[4][4];
        #pragma unroll
        for (int r = 0; r < 4; ++r)
            #pragma unroll
            for (int s = 0; s < 4; ++s) g[r][s] = Gs[bp + r][cp + s];
        float rde[4], rdo[4];
        #pragma unroll
        for (int r = 0; r < 4; ++r) {
            rde[r] =  g[r][0] + 7.f * g[r][1] - 9.f * g[r][2] + g[r][3];
            rdo[r] = -g[r][0] + 9.f * g[r][1] - 7.f * g[r][2] - g[r][3];
        }
        const float hee = ( rde[0] + 7.f*rde[1] - 9.f*rde[2] + rde[3]) * (1.f/256.f);
        const float heo = ( rdo[0] + 7.f*rdo[1] - 9.f*rdo[2] + rdo[3]) * (1.f/256.f);
        const float hoe = (-rde[0] + 9.f*rde[1] - 7.f*rde[2] - rde[3]) * (1.f/256.f);
        const float hoo = (-rdo[0] + 9.f*rdo[1] - 7.f*rdo[2] - rdo[3]) * (1.f/256.f);
        const int b0 = 2 * bp, c0 = 2 * cp;
        {
            float p = hee * invT, jo = mx[b0] * my[c0] * invT2;
            mi += p * (__logf(p + 1e-8f) - __logf(jo + 1e-8f));
        }
        {
            float p = heo * invT, jo = mx[b0] * my[c0 + 1] * invT2;
            mi += p * (__logf(p + 1e-8f) - __logf(jo + 1e-8f));
        }
        {
            float p = hoe * invT, jo = mx[b0 + 1] * my[c0] * invT2;
            mi += p * (__logf(p + 1e-8f) - __logf(jo + 1e-8f));
        }
        {
            float p = hoo * invT, jo = mx[b0 + 1] * my[c0 + 1] * invT2;
            mi += p * (__logf(p + 1e-8f) - __logf(jo + 1e-8f));
        }
    }
    #pragma unroll
    for (int o = 32; o > 0; o >>= 1) mi += __shfl_down(mi, o, 64);
    if ((tid & 63) == 0) red[tid >> 6] = mi;
    __syncthreads();
    if (tid == 0) {
        float t = 0.f;
        #pragma unroll
        for (int i = 0; i < 16; ++i) t += red[i];
        atomicAdd(&out[0], t);
    }
}

extern "C" void kernel_launch(void* const* d_in, const int* in_sizes, int n_in,
                              void* d_out, int out_size, void* d_ws, size_t ws_size,
                              hipStream_t stream) {
    const float* im1 = (const float*)d_in[0];
    const float* im2 = (const float*)d_in[1];
    float* out = (float*)d_out;
    float* hg  = (float*)d_ws;   // [8][32][32] f32 = 32 KB

    (void)hipMemsetAsync(d_ws, 0, NBATCH * 1024 * sizeof(float), stream);
    hgram_kernel<<<dim3(KSLICES, NBATCH), dim3(256), 0, stream>>>(im1, im2, hg, out);
    finalize_kernel<<<dim3(NBATCH), dim3(1024), 0, stream>>>(hg, out);
}